// Round 18
// baseline (38.261 us; speedup 1.0000x reference)
//
#include <hip/hip_runtime.h>

#define F_ALPHA 0.25f
#define F_EPS   1e-8f

// One pred per WAVE (4 preds/block, grid = N/4).
// All pred state is scalar (9 floats + 1 pointer) — no arrays, no lambda,
// no cross-wave LDS sharing (each wave writes+reads only fcls[w][.]),
// hence no __syncthreads. Targets swept at t = lane + 64k (coalesced).
// R17 bug fixed: macro local renamed (BODY(t) was self-shadowing `t`).
__global__ void __launch_bounds__(256)
fused_cost_kernel(const float* __restrict__ logits,      // [N, C]
                  const float4* __restrict__ pred_boxes, // [N]
                  const float4* __restrict__ tgt_boxes,  // [T]
                  const int* __restrict__ tgt_ids,       // [T]
                  float* __restrict__ out,               // [N, T]
                  int N, int C, int T) {
    __shared__ float fcls[4][92];                        // per-wave focal row
    const int w    = threadIdx.x >> 6;
    const int lane = threadIdx.x & 63;
    const int n    = blockIdx.x * 4 + w;

    // ---- phase 1: this wave's prescaled focal row (2*cls + 2) ----
    const float* lrow = logits + (size_t)n * C;
    for (int c = lane; c < C; c += 64) {
        float x = lrow[c];
        float p = 1.0f / (1.0f + expf(-x));
        float om = 1.0f - p;
        float pos = F_ALPHA * om * om * (-logf(p + F_EPS));
        float neg = (1.0f - F_ALPHA) * p * p * (-logf(om + F_EPS));
        fcls[w][c] = 2.0f * (pos - neg) + 2.0f;
    }
    // wave-internal LDS write->read: in-order within a wave; no barrier needed.

    // ---- pred state: scalars only ----
    float4 pb = pred_boxes[n];
    const float pcx = pb.x, pcy = pb.y, pw = pb.z, ph = pb.w;
    const float px1 = fmaf(-0.5f, pw, pcx), py1 = fmaf(-0.5f, ph, pcy);
    const float px2 = fmaf( 0.5f, pw, pcx), py2 = fmaf( 0.5f, ph, pcy);
    const float parea = pw * ph;
    float* __restrict__ orow = out + (size_t)n * T;

#define BODY(TIDX) {                                                        \
        const int tt = (TIDX);                                              \
        float4 tb = tgt_boxes[tt];                                          \
        int id = tgt_ids[tt];                                               \
        float cls = fcls[w][id];                                            \
        float tx1 = fmaf(-0.5f, tb.z, tb.x), ty1 = fmaf(-0.5f, tb.w, tb.y); \
        float tx2 = fmaf( 0.5f, tb.z, tb.x), ty2 = fmaf( 0.5f, tb.w, tb.y); \
        float ax = fmaxf(px1, tx1), bx = fminf(px2, tx2);                   \
        float ay = fmaxf(py1, ty1), by = fminf(py2, ty2);                   \
        float dx = bx - ax, dy = by - ay;                                   \
        float inter = fmaxf(dx, 0.0f) * fmaxf(dy, 0.0f);                    \
        float uni = (parea + tb.z * tb.w) - inter;                          \
        float ew = (pw + tb.z) - dx, eh = (ph + tb.w) - dy;                 \
        float earea = ew * eh;                                              \
        float l1 = (fabsf(pcx - tb.x) + fabsf(pcy - tb.y))                  \
                 + (fabsf(pw - tb.z) + fabsf(ph - tb.w));                   \
        float num = fmaf(uni, uni, inter * earea);                          \
        float v = fmaf(5.0f, l1, cls);                                      \
        v = fmaf(-2.0f, num * __builtin_amdgcn_rcpf(uni * earea), v);       \
        orow[tt] = v;                                                       \
    }

    // ---- phase 2: sweep own pred's targets, unrolled x2 ----
    int t = lane;
    for (; t + 64 < T; t += 128) { BODY(t); BODY(t + 64); }
    for (; t < T; t += 64) BODY(t);
#undef BODY
}

extern "C" void kernel_launch(void* const* d_in, const int* in_sizes, int n_in,
                              void* d_out, int out_size, void* d_ws, size_t ws_size,
                              hipStream_t stream) {
    const float* logits = (const float*)d_in[0];   // [bs, Q, C]
    const float* pboxes = (const float*)d_in[1];   // [bs, Q, 4]
    const float* tboxes = (const float*)d_in[2];   // [T, 4]
    const int*   tids   = (const int*)d_in[3];     // [T]

    int N = in_sizes[1] / 4;          // bs*Q = 14400
    int C = in_sizes[0] / N;          // 91
    int T = in_sizes[2] / 4;          // 1600

    int grid = N / 4;                 // 3600
    fused_cost_kernel<<<grid, 256, 0, stream>>>(
        logits, (const float4*)pboxes, (const float4*)tboxes, tids,
        (float*)d_out, N, C, T);
}

// Round 19
// 35.564 us; speedup vs baseline: 1.0758x; 1.0758x over previous
//
#include <hip/hip_runtime.h>

#define F_ALPHA 0.25f
#define F_EPS   1e-8f
#define NB 4   // preds per block

// R14 structure; per-pair math replaced by an exact 28-instruction inline-asm
// block (the compiler was executing ~75 VALU/pair for ~33 ops of source math).
__global__ void __launch_bounds__(256, 4)
fused_cost_kernel(const float* __restrict__ logits,      // [N, C]
                  const float4* __restrict__ pred_boxes, // [N]
                  const float4* __restrict__ tgt_boxes,  // [T]
                  const int* __restrict__ tgt_ids,       // [T]
                  float* __restrict__ out,               // [N, T]
                  int N, int C, int T) {
    __shared__ float4 fclsT[96];                         // [class] -> NB costs
    const int n0  = blockIdx.x * NB;
    const int tid = threadIdx.x;

    // ---- phase 1: wave w computes pred (n0+w)'s focal row, transposed ----
    {
        const int w = tid >> 6, l = tid & 63;
        const float* lrow = logits + (size_t)(n0 + w) * C;
        for (int c = l; c < C; c += 64) {
            float x = lrow[c];
            float p = 1.0f / (1.0f + expf(-x));
            float om = 1.0f - p;
            float pos = F_ALPHA * om * om * (-logf(p + F_EPS));
            float neg = (1.0f - F_ALPHA) * p * p * (-logf(om + F_EPS));
            ((float*)fclsT)[c * NB + w] = 2.0f * (pos - neg) + 2.0f; // 2*cls+2
        }
    }

    // pred-side params (block-uniform)
    float pcx[NB], pcy[NB], pw_[NB], ph_[NB];
    float px1[NB], py1[NB], px2[NB], py2[NB], parea[NB];
    float* op[NB];
#pragma unroll
    for (int i = 0; i < NB; ++i) {
        const int n = n0 + i;                            // N % NB == 0
        float4 pb = pred_boxes[n];
        pcx[i] = pb.x; pcy[i] = pb.y; pw_[i] = pb.z; ph_[i] = pb.w;
        px1[i] = fmaf(-0.5f, pb.z, pb.x);  py1[i] = fmaf(-0.5f, pb.w, pb.y);
        px2[i] = fmaf( 0.5f, pb.z, pb.x);  py2[i] = fmaf( 0.5f, pb.w, pb.y);
        parea[i] = pb.z * pb.w;
        op[i] = out + (size_t)n * T;
    }
    __syncthreads();

    auto body = [&](int t) {
        float4 tb = tgt_boxes[t];                        // unit-stride float4
        int id = tgt_ids[t];                             // unit-stride dword
        float4 cls4 = fclsT[id];                         // one ds_read_b128
        const float clsv[NB] = {cls4.x, cls4.y, cls4.z, cls4.w};

        float tx1 = fmaf(-0.5f, tb.z, tb.x), ty1 = fmaf(-0.5f, tb.w, tb.y);
        float tx2 = fmaf( 0.5f, tb.z, tb.x), ty2 = fmaf( 0.5f, tb.w, tb.y);
        float tarea = tb.z * tb.w;

#pragma unroll
        for (int i = 0; i < NB; ++i) {
            float S   = parea[i] + tarea;                // union base
            float PWZ = pw_[i] + tb.z;                   // enclosing-w base
            float PHZ = ph_[i] + tb.w;                   // enclosing-h base
            float v, q0, q1, q2, q3;
            asm("v_max_f32 %1, %5, %16\n\t"              // ax = max(px1,tx1)
                "v_min_f32 %2, %6, %17\n\t"              // bx = min(px2,tx2)
                "v_sub_f32 %1, %2, %1\n\t"               // dx = bx-ax
                "v_max_f32 %2, %7, %18\n\t"              // ay
                "v_min_f32 %3, %8, %19\n\t"              // by
                "v_sub_f32 %2, %3, %2\n\t"               // dy = by-ay
                "v_sub_f32 %3, %9, %1\n\t"               // ew = PWZ - dx
                "v_sub_f32 %4, %10, %2\n\t"              // eh = PHZ - dy
                "v_mul_f32 %3, %3, %4\n\t"               // earea = ew*eh
                "v_max_f32 %1, 0, %1\n\t"                // iw = max(dx,0)
                "v_max_f32 %2, 0, %2\n\t"                // ih = max(dy,0)
                "v_mul_f32 %1, %1, %2\n\t"               // inter = iw*ih
                "v_sub_f32 %2, %11, %1\n\t"              // uni = S - inter
                "v_mul_f32 %4, %2, %3\n\t"               // den = uni*earea
                "v_rcp_f32 %4, %4\n\t"                   // r = rcp(den)
                "v_mul_f32 %1, %1, %3\n\t"               // inter*earea
                "v_fma_f32 %1, %2, %2, %1\n\t"           // num = uni^2 + i*e
                "v_mul_f32 %1, %1, %4\n\t"               // q = num*r
                "v_sub_f32 %2, %12, %20\n\t"             // pcx - tbx
                "v_sub_f32 %3, %13, %21\n\t"             // pcy - tby
                "v_add_f32 %2, |%2|, |%3|\n\t"           // |dx|+|dy|
                "v_sub_f32 %3, %14, %22\n\t"             // pw - tbz
                "v_sub_f32 %4, %15, %23\n\t"             // ph - tbw
                "v_add_f32 %3, |%3|, |%4|\n\t"           // |dw|+|dh|
                "v_add_f32 %2, %2, %3\n\t"               // l1
                "v_fma_f32 %3, 4.0, %2, %24\n\t"         // 4*l1 + cls
                "v_add_f32 %2, %2, %3\n\t"               // 5*l1 + cls
                "v_fma_f32 %0, -2.0, %1, %2"             // v = -2q + 5l1 + cls
                : "=&v"(v), "=&v"(q0), "=&v"(q1), "=&v"(q2), "=&v"(q3)
                : "v"(px1[i]), "v"(px2[i]), "v"(py1[i]), "v"(py2[i]),
                  "v"(PWZ), "v"(PHZ), "v"(S),
                  "v"(pcx[i]), "v"(pcy[i]), "v"(pw_[i]), "v"(ph_[i]),
                  "v"(tx1), "v"(tx2), "v"(ty1), "v"(ty2),
                  "v"(tb.x), "v"(tb.y), "v"(tb.z), "v"(tb.w), "v"(clsv[i]));
            op[i][t] = v;                                // coalesced dword store
        }
    };

    // ---- phase 2: unrolled-by-2 target sweep ----
    int t = tid;
    for (; t + 256 < T; t += 512) { body(t); body(t + 256); }
    for (; t < T; t += 256) body(t);
}

extern "C" void kernel_launch(void* const* d_in, const int* in_sizes, int n_in,
                              void* d_out, int out_size, void* d_ws, size_t ws_size,
                              hipStream_t stream) {
    const float* logits = (const float*)d_in[0];   // [bs, Q, C]
    const float* pboxes = (const float*)d_in[1];   // [bs, Q, 4]
    const float* tboxes = (const float*)d_in[2];   // [T, 4]
    const int*   tids   = (const int*)d_in[3];     // [T]

    int N = in_sizes[1] / 4;          // bs*Q = 14400
    int C = in_sizes[0] / N;          // 91
    int T = in_sizes[2] / 4;          // 1600

    int grid = N / NB;                // 3600
    fused_cost_kernel<<<grid, 256, 0, stream>>>(
        logits, (const float4*)pboxes, (const float4*)tboxes, tids,
        (float*)d_out, N, C, T);
}

// Round 20
// 31.736 us; speedup vs baseline: 1.2056x; 1.1206x over previous
//
#include <hip/hip_runtime.h>

#define F_ALPHA 0.25f
#define F_EPS   1e-8f
#define NB 4   // preds per block

// R16 base + SGPR store bases: op[i] row pointers forced uniform via
// readfirstlane so stores lower to saddr form (SGPR base + shared voffset),
// removing ~10 VALU/body of 64-bit per-store address arithmetic.
__global__ void __launch_bounds__(256, 4)
fused_cost_kernel(const float* __restrict__ logits,      // [N, C]
                  const float4* __restrict__ pred_boxes, // [N]
                  const float4* __restrict__ tgt_boxes,  // [T]
                  const int* __restrict__ tgt_ids,       // [T]
                  float* __restrict__ out,               // [N, T]
                  int N, int C, int T) {
    __shared__ float4 fclsT[96];                         // [class] -> NB costs
    const int n0  = blockIdx.x * NB;
    const int tid = threadIdx.x;

    // ---- phase 1: wave w computes pred (n0+w)'s focal row, transposed ----
    {
        const int w = tid >> 6, l = tid & 63;
        const float* lrow = logits + (size_t)(n0 + w) * C;
        for (int c = l; c < C; c += 64) {
            float x = lrow[c];
            float p = 1.0f / (1.0f + expf(-x));
            float om = 1.0f - p;
            float pos = F_ALPHA * om * om * (-logf(p + F_EPS));
            float neg = (1.0f - F_ALPHA) * p * p * (-logf(om + F_EPS));
            ((float*)fclsT)[c * NB + w] = 2.0f * (pos - neg) + 2.0f; // 2*cls+2
        }
    }

    // pred-side params (block-uniform)
    float pcx[NB], pcy[NB], pw_[NB], ph_[NB];
    float px1[NB], py1[NB], px2[NB], py2[NB], parea[NB];
    float* op[NB];
#pragma unroll
    for (int i = 0; i < NB; ++i) {
        const int n = n0 + i;                            // N % NB == 0
        float4 pb = pred_boxes[n];
        pcx[i] = pb.x; pcy[i] = pb.y; pw_[i] = pb.z; ph_[i] = pb.w;
        px1[i] = fmaf(-0.5f, pb.z, pb.x);  py1[i] = fmaf(-0.5f, pb.w, pb.y);
        px2[i] = fmaf( 0.5f, pb.z, pb.x);  py2[i] = fmaf( 0.5f, pb.w, pb.y);
        parea[i] = pb.z * pb.w;
        // force row base into SGPRs: provably uniform -> saddr stores
        uintptr_t a = (uintptr_t)(out + (size_t)n * T);
        uint32_t lo = __builtin_amdgcn_readfirstlane((uint32_t)a);
        uint32_t hi = __builtin_amdgcn_readfirstlane((uint32_t)(a >> 32));
        op[i] = (float*)(((uintptr_t)hi << 32) | (uintptr_t)lo);
    }
    __syncthreads();

    auto body = [&](int t) {
        float4 tb = tgt_boxes[t];                        // unit-stride float4
        int id = tgt_ids[t];                             // unit-stride dword
        float4 cls4 = fclsT[id];                         // one ds_read_b128
        const float clsv[NB] = {cls4.x, cls4.y, cls4.z, cls4.w};

        float tx1 = fmaf(-0.5f, tb.z, tb.x), ty1 = fmaf(-0.5f, tb.w, tb.y);
        float tx2 = fmaf( 0.5f, tb.z, tb.x), ty2 = fmaf( 0.5f, tb.w, tb.y);
        float tarea = tb.z * tb.w;

#pragma unroll
        for (int i = 0; i < NB; ++i) {
            float ax = fmaxf(px1[i], tx1), bx = fminf(px2[i], tx2);
            float ay = fmaxf(py1[i], ty1), by = fminf(py2[i], ty2);
            float dx = bx - ax, dy = by - ay;
            float iw = fmaxf(dx, 0.0f), ih = fmaxf(dy, 0.0f);
            float inter = iw * ih;
            float uni = (parea[i] + tarea) - inter;

            float ew = (pw_[i] + tb.z) - dx;             // enclosing identity
            float eh = (ph_[i] + tb.w) - dy;
            float earea = ew * eh;

            float l1 = (fabsf(pcx[i] - tb.x) + fabsf(pcy[i] - tb.y))
                     + (fabsf(pw_[i] - tb.z) + fabsf(ph_[i] - tb.w));

            // 2*inter/uni + 2*uni/earea = 2*(inter*earea + uni^2)*rcp(uni*earea)
            float den = uni * earea;
            float r   = __builtin_amdgcn_rcpf(den);
            float num = fmaf(uni, uni, inter * earea);

            float v = fmaf(5.0f, l1, clsv[i]);           // 5*l1 + 2*cls + 2
            v = fmaf(-2.0f, num * r, v);
            op[i][t] = v;                                // saddr store, shared voff
        }
    };

    // ---- phase 2: unroll-4 target sweep (R16 best) ----
    int t = tid;
    for (; t + 768 < T; t += 1024) {
        body(t); body(t + 256); body(t + 512); body(t + 768);
    }
    for (; t < T; t += 256) body(t);
}

extern "C" void kernel_launch(void* const* d_in, const int* in_sizes, int n_in,
                              void* d_out, int out_size, void* d_ws, size_t ws_size,
                              hipStream_t stream) {
    const float* logits = (const float*)d_in[0];   // [bs, Q, C]
    const float* pboxes = (const float*)d_in[1];   // [bs, Q, 4]
    const float* tboxes = (const float*)d_in[2];   // [T, 4]
    const int*   tids   = (const int*)d_in[3];     // [T]

    int N = in_sizes[1] / 4;          // bs*Q = 14400
    int C = in_sizes[0] / N;          // 91
    int T = in_sizes[2] / 4;          // 1600

    int grid = N / NB;                // 3600
    fused_cost_kernel<<<grid, 256, 0, stream>>>(
        logits, (const float4*)pboxes, (const float4*)tboxes, tids,
        (float*)d_out, N, C, T);
}